// Round 4
// baseline (140.677 us; speedup 1.0000x reference)
//
#include <hip/hip_runtime.h>
#include <hip/hip_bf16.h>

#define BATCH   4
#define NBOX    8192
#define BLOCK   256
#define TSZ     256                  // tile size (rows & cols)
#define NT      (NBOX / TSZ)         // 32 tiles per batch
#define NPAIRS  (NT * (NT + 1) / 2)  // 528 tile-pairs per batch
#define NBINS   2048
#define SUBS    8                    // sub-slices per batch for the sort
#define SUBSZ   (NBOX / SUBS)        // 1024 boxes per slice
#define STH     512                  // sort kernel threads

__device__ __forceinline__ float bf2f(unsigned short u) {
    union { unsigned int i; float f; } c;
    c.i = ((unsigned int)u) << 16;
    return c.f;
}

__device__ __forceinline__ bool box_plausible(float x1, float y1, float x2, float y2) {
    bool ok = (x1 == x1) && (y1 == y1) && (x2 == x2) && (y2 == y2);
    ok = ok && fabsf(x1) < 1e4f && fabsf(y1) < 1e4f && fabsf(x2) < 1e4f && fabsf(y2) < 1e4f;
    ok = ok && x1 >= -1.0f && x1 <= 300.0f && y1 >= -1.0f && y1 <= 300.0f;
    const float w = x2 - x1, h = y2 - y1;
    ok = ok && w >= -0.1f && w <= 80.0f && h >= -0.1f && h <= 80.0f;
    return ok;
}

// Wave-redundant dtype probe; all waves deterministically agree. true -> f32.
__device__ __forceinline__ bool wave_probe_is_f32(const void* boxes_raw) {
    const int lane = threadIdx.x & 63;
    const float* bf = (const float*)boxes_raw;
    const bool okf = box_plausible(bf[lane * 4 + 0], bf[lane * 4 + 1],
                                   bf[lane * 4 + 2], bf[lane * 4 + 3]);
    const unsigned short* bh = (const unsigned short*)boxes_raw;
    const bool okh = box_plausible(bf2f(bh[lane * 4 + 0]), bf2f(bh[lane * 4 + 1]),
                                   bf2f(bh[lane * 4 + 2]), bf2f(bh[lane * 4 + 3]));
    const unsigned long long mf = __ballot(okf);
    const unsigned long long mh = __ballot(okh);
    return __popcll(mf) >= __popcll(mh);
}

__device__ __forceinline__ float4 load_box(const void* boxes_raw, size_t idx, bool isf32) {
    if (isf32) {
        return reinterpret_cast<const float4*>(boxes_raw)[idx];
    } else {
        const ushort4 u = reinterpret_cast<const ushort4*>(boxes_raw)[idx];
        return make_float4(bf2f(u.x), bf2f(u.y), bf2f(u.z), bf2f(u.w));
    }
}

__device__ __forceinline__ float load_score(const void* scores_raw, size_t idx, bool isf32) {
    return isf32 ? ((const float*)scores_raw)[idx]
                 : bf2f(((const unsigned short*)scores_raw)[idx]);
}

// Sort key is x2: 2048 bins over [0,256), 0.125 units/bin.
__device__ __forceinline__ int key_bin(float v) {
    const int bb = (int)(v * 8.0f);
    return min(NBINS - 1, max(0, bb));
}

// exp(-iou/0.5) = exp2(iou * (-2 log2 e)); arg in [-2.886, 0] -> raw v_exp ok
#define CEXP (-2.8853900817779268f)

__device__ __forceinline__ float pair_weight(
    float ix1, float iy1, float ix2, float iy2, float iarea,
    const float4& bj, float jarea)
{
    float w = fminf(ix2, bj.z) - fmaxf(ix1, bj.x);
    float h = fminf(iy2, bj.w) - fmaxf(iy1, bj.y);
    w = fmaxf(w, 0.0f);
    h = fmaxf(h, 0.0f);
    const float inter = w * h;
    const float uni   = iarea + jarea - inter;          // >= ~1 always
    const float arg   = (CEXP * inter) * __builtin_amdgcn_rcpf(uni);
    return __builtin_amdgcn_exp2f(arg);
}

// Single fused sort kernel (32 blocks, 512 threads). Every block REDUNDANTLY
// histograms the full batch (deterministic -> identical in all blocks).
// Sort key x2; per-bin atomicMin(x1) provides tile-level min-x1 meta used for
// the pairlist + finish correction. Zeroes BOTH adj and adjc.
__global__ __launch_bounds__(STH) void sort_kernel(
    const void* __restrict__ boxes_raw, const void* __restrict__ scores_raw,
    float4* __restrict__ sboxes, float* __restrict__ sscores,
    float* __restrict__ adj, float* __restrict__ adjc,        // (B,N) zeroed
    float* __restrict__ minx1c, float* __restrict__ maxx2c,   // (B,NT)
    int* __restrict__ pairlist, int* __restrict__ count)      // (B,NPAIRS),(B)
{
    __shared__ int hist[NBINS];          // full-batch counts -> then sex
    __shared__ int bmin[NBINS];          // per-bin min x1 bits (x1 >= 0 -> monotone)
    __shared__ int hist2[NBINS];         // earlier-subs counts -> then loff
    __shared__ int wsum[STH / 64];
    __shared__ float sminT[NT], smaxT[NT];
    __shared__ int scnt;

    const int b    = blockIdx.x / SUBS;
    const int sub  = blockIdx.x % SUBS;
    const int tid  = threadIdx.x;
    const int lane = tid & 63;
    const int wv   = tid >> 6;
    const bool isf32 = wave_probe_is_f32(boxes_raw);
    const size_t base = (size_t)b * NBOX;

#pragma unroll
    for (int i = 0; i < NBINS / STH; i++) {
        hist[i * STH + tid]  = 0;
        bmin[i * STH + tid]  = 0x7f800000;   // +inf
        hist2[i * STH + tid] = 0;
    }
    if (tid == 0) scnt = 0;
    {   // zero adj + adjc: 32 blocks x 1024 floats each covers B*NBOX
        const size_t z = (size_t)blockIdx.x * 1024;
        adj[z + tid] = 0.0f;
        adj[z + STH + tid] = 0.0f;
        adjc[z + tid] = 0.0f;
        adjc[z + STH + tid] = 0.0f;
    }
    __syncthreads();

    // full-batch histogram on x2 + per-bin min x1 (identical in every block),
    // with the earlier-subs histogram folded in (i < sub*SUBSZ prefix).
    const int sublim = sub * SUBSZ;
#pragma unroll
    for (int k = 0; k < NBOX / STH; k++) {
        const int i = k * STH + tid;
        const float4 bx = load_box(boxes_raw, base + i, isf32);
        const int bin = key_bin(bx.z);
        atomicAdd(&hist[bin], 1);
        atomicMin(&bmin[bin], __float_as_int(bx.x));
        if (i < sublim) atomicAdd(&hist2[bin], 1);
    }
    __syncthreads();

    // exclusive scan of hist: 4 bins/thread + wave shfl scan + cross-wave
    {
        int tot[4], cum[4];
        int run = 0;
#pragma unroll
        for (int i = 0; i < 4; i++) {
            tot[i] = hist[tid * 4 + i];
            run += tot[i]; cum[i] = run;
        }
        int v = run;
#pragma unroll
        for (int d = 1; d < 64; d <<= 1) {
            const int u = __shfl_up(v, d);
            if (lane >= d) v += u;
        }
        if (lane == 63) wsum[wv] = v;
        __syncthreads();
        int wb = 0;
        for (int w = 0; w < wv; w++) wb += wsum[w];
        const int tb = wb + v - run;                 // exclusive thread base
#pragma unroll
        for (int i = 0; i < 4; i++) {
            const int bin = tid * 4 + i;
            const int e = tb + cum[i] - tot[i];      // exclusive bin start
            const int m = hist2[bin];                // my-sub prefix in bin
            hist[bin]  = e;                          // sex (own bins only)
            hist2[bin] = e + m;                      // loff (own bins only)
        }
    }
    __syncthreads();

    // tile meta: binary search on sex (nondecreasing, sex[0]==0).
    if (tid < NT) {
        int p = tid * TSZ;
        int lo = 0, hi = NBINS - 1;
        while (lo < hi) { const int mid = (lo + hi + 1) >> 1;
                          if (hist[mid] <= p) lo = mid; else hi = mid - 1; }
        const int Bf = lo;
        p = tid * TSZ + TSZ - 1;
        lo = 0; hi = NBINS - 1;
        while (lo < hi) { const int mid = (lo + hi + 1) >> 1;
                          if (hist[mid] <= p) lo = mid; else hi = mid - 1; }
        const int Bl = lo;
        float mn = 3.4e38f;
        for (int q = Bf; q <= Bl; q++) mn = fminf(mn, __int_as_float(bmin[q]));
        const float mx = (float)(Bl + 1) * 0.125f;   // upper bound of tile max x2
        sminT[tid] = mn; smaxT[tid] = mx;
        if (sub == 0) {
            minx1c[b * NT + tid] = mn;
            maxx2c[b * NT + tid] = mx;
        }
    }
    __syncthreads();

    // compacted live pair list (sub==0 only; same compares finish will use)
    if (sub == 0) {
        for (int q = tid; q < NPAIRS; q += STH) {
            int p = q, it = 0;
            while (p >= NT - it) { p -= NT - it; it++; }
            const int jt = it + p;
            const bool live = !((smaxT[it] < sminT[jt]) || (smaxT[jt] < sminT[it]));
            if (live) {
                const int idx = atomicAdd(&scnt, 1);
                pairlist[b * NPAIRS + idx] = (it << 8) | jt;
            }
        }
    }

    // scatter my slice (by x2 bin)
#pragma unroll
    for (int k = 0; k < SUBSZ / STH; k++) {
        const int i = sub * SUBSZ + k * STH + tid;
        const float4 bx = load_box(boxes_raw, base + i, isf32);
        const float  sc = load_score(scores_raw, base + i, isf32);
        const int pos = atomicAdd(&hist2[key_bin(bx.z)], 1);
        sboxes[base + pos]  = bx;
        sscores[base + pos] = sc;
    }

    __syncthreads();
    if (sub == 0 && tid == 0) count[b] = scnt;
}

// Per-tile x1-reorder via rank-scan (1 barrier, no bitonic). Columns of each
// tile reordered ascending-x1 so the 4 column groups of 64 are exact
// x1-quartiles with EXACT per-group min-x1 (cgmin). cinv maps x2-rank ->
// x1-position for the finish kernel's adjc gather.
__global__ __launch_bounds__(TSZ) void perm_kernel(
    const float4* __restrict__ sboxes, const float* __restrict__ sscores,
    float4* __restrict__ cboxes, float2* __restrict__ cas,
    int* __restrict__ cinv,             // (B,N) x2-rank -> x1-pos (tile-rel)
    float* __restrict__ cgmin)          // (B,NT,4) exact colgroup min x1
{
    __shared__ float sx1[TSZ];
    const int tile = blockIdx.x;              // 0..B*NT-1
    const size_t gbase = (size_t)tile * TSZ;  // == b*NBOX + t*TSZ (contiguous)
    const int tid = threadIdx.x;

    const float4 u = sboxes[gbase + tid];
    const float sc = sscores[gbase + tid];
    sx1[tid] = u.x;
    __syncthreads();

    // rank of my x1 within the tile (ties broken by index -> permutation)
    int rank = 0;
#pragma unroll 8
    for (int j = 0; j < TSZ; j++) {
        const float v = sx1[j];
        rank += (v < u.x || (v == u.x && j < tid)) ? 1 : 0;
    }

    cboxes[gbase + rank] = u;
    cas[gbase + rank] = make_float2((u.z - u.x) * (u.w - u.y), sc);
    cinv[gbase + tid] = rank;
    if ((rank & 63) == 0) cgmin[tile * 4 + (rank >> 6)] = u.x;
}

// adj over live tile-pairs. Rows x2-sorted (global sort): rowgroup k
// (ranks k*64+lane) has tight max-x2 = lane63's x2 + one bin (0.125).
// Columns per-tile x1-sorted: wave wv owns colgroup wv with EXACT min-x1.
// Cell (k,wv) skipped iff rowmax_x2[k] < cgmin[jt][wv] -> all its pairs have
// weight exactly 1 -> exact corrections:
//   rows in skipped cells: wave wv seeds its OWN colgroup score-sum (ws)
//   wave's columns:        ccorr = sum of skipped rowgroup score-sums
// Col partials go to adjc in x1-order (CONTIGUOUS atomics; finish unpermutes
// via cinv). 8 blocks/CU for DS-latency hiding (round-3 lesson: at 4 blocks/CU
// the ds_read->compute->shfl chain stalls 50%+ once VALU work is trimmed).
__global__ __launch_bounds__(BLOCK, 8) void soft_nms_adj_kernel(
    const float4* __restrict__ sboxes,   // (B,N) x2-sorted boxes (rows)
    const float* __restrict__ sscores,   // (B,N) x2-sorted scores
    const float4* __restrict__ cboxes,   // (B,N) per-tile x1-sorted boxes (cols)
    const float2* __restrict__ cas,      // (B,N) col area,score
    const float* __restrict__ cgmin,     // (B,NT,4) exact colgroup min x1
    const int* __restrict__ pairlist,    // (B,NPAIRS) compacted live pairs
    const int* __restrict__ count,       // (B)
    float* __restrict__ adj,             // (B,N) row accum (x2-order), zeroed
    float* __restrict__ adjc)            // (B,N) col accum (x1-order), zeroed
{
    __shared__ float4 sbox[TSZ];          // j-tile cols: x1,y1,x2,y2 (x1-sorted)
    __shared__ float2 sas[TSZ];           // j-tile cols: area, score
    __shared__ float  srow[4][TSZ];       // per-wave row partials

    const int bid = blockIdx.x;
    const int b   = bid / NPAIRS;
    const int p   = bid % NPAIRS;
    if (p >= count[b]) return;            // dead block: one scalar load
    const int pr = pairlist[b * NPAIRS + p];
    const int it = pr >> 8, jt = pr & 255;

    const int tid  = threadIdx.x;
    const int lane = tid & 63;
    const int wv   = tid >> 6;
    const size_t base = (size_t)b * NBOX;

    // stage j-tile cols into LDS; ws = this wave's colgroup score sum
    float ws;
    {
        const int jg = jt * TSZ + tid;
        const float4 uj = cboxes[base + jg];
        sbox[tid] = uj;
        const float2 asv = cas[base + jg];
        sas[tid]  = asv;
        float w0 = asv.y;
#pragma unroll
        for (int off = 32; off > 0; off >>= 1) w0 += __shfl_xor(w0, off);
        ws = w0;                           // all lanes hold it
    }

    // rows: thread owns rows {k*64 + lane} of the i-tile (same set in every wave)
    float rx1[4], ry1[4], rx2[4], ry2[4], rar[4], rsc[4];
#pragma unroll
    for (int k = 0; k < 4; k++) {
        const int ig = it * TSZ + k * 64 + lane;
        const float4 ui = sboxes[base + ig];
        rx1[k] = ui.x; ry1[k] = ui.y; rx2[k] = ui.z; ry2[k] = ui.w;
        rar[k] = (ui.z - ui.x) * (ui.w - ui.y);
        rsc[k] = sscores[base + ig];
    }

    // per-wave cell-skip prefix (off-diagonal only; diagonal provably 0)
    int kstart = 0;
    if (it != jt) {
        const float cg = cgmin[(b * NT + jt) * 4 + wv];
#pragma unroll
        for (int k = 0; k < 4; k++) {
            const float gmax = __shfl(rx2[k], 63) + 0.125f;  // bin slack
            if (kstart == k && gmax < cg) kstart = k + 1;
        }
    }
    // column-side correction: sum of scores of skipped rowgroups
    float ccorr = 0.0f;
    if (kstart > 0) {
#pragma unroll
        for (int k = 0; k < 4; k++) {
            if (k < kstart) {
                float gs = rsc[k];
#pragma unroll
                for (int off = 32; off > 0; off >>= 1) gs += __shfl_xor(gs, off);
                ccorr += gs;
            }
        }
    }

    __syncthreads();

    // row-side seeds: THIS wave's skipped cells contribute ws to its rows;
    // the cross-wave srow combine sums per-wave contributions exactly once.
    float accr[4];
#pragma unroll
    for (int k = 0; k < 4; k++) accr[k] = (k < kstart) ? ws : 0.0f;

    const int wvbase = wv * 64;

    if (it == jt) {
        // diagonal: full ordered pairs, row side only (includes i==j)
#pragma unroll 2
        for (int t = 0; t < 64; t++) {
            const int idx = wvbase + ((lane + t) & 63);
            const float4 bj = sbox[idx];
            const float2 as = sas[idx];
#pragma unroll
            for (int k = 0; k < 4; k++) {
                const float e = pair_weight(rx1[k], ry1[k], rx2[k], ry2[k], rar[k], bj, as.x);
                accr[k] = fmaf(e, as.y, accr[k]);
            }
        }
    } else {
#define OFFD_LOOP(KS)                                                          \
        {                                                                      \
            float accc = ccorr;                                                \
            _Pragma("unroll 2")                                                \
            for (int t = 0; t < 64; t++) {                                     \
                const int idx = wvbase + ((lane + t) & 63);                    \
                const float4 bj = sbox[idx];                                   \
                const float2 as = sas[idx];                                    \
                float c = 0.0f;                                                \
                _Pragma("unroll")                                              \
                for (int k = KS; k < 4; ++k) {                                 \
                    const float e = pair_weight(rx1[k], ry1[k], rx2[k], ry2[k],\
                                                rar[k], bj, as.x);             \
                    accr[k] = fmaf(e, as.y, accr[k]);                          \
                    c = fmaf(e, rsc[k], c);                                    \
                }                                                              \
                accc += __shfl(c, (lane - t) & 63);                            \
            }                                                                  \
            atomicAdd(&adjc[base + jt * TSZ + wvbase + lane], accc);           \
        }
        switch (kstart) {
            case 0: OFFD_LOOP(0); break;
            case 1: OFFD_LOOP(1); break;
            case 2: OFFD_LOOP(2); break;
            case 3: OFFD_LOOP(3); break;
            default:   // kstart == 4: wave fully skipped; corrections only
                atomicAdd(&adjc[base + jt * TSZ + wvbase + lane], ccorr);
                break;
        }
#undef OFFD_LOOP
    }

    // combine row partials across the 4 waves via LDS, one atomic per row
#pragma unroll
    for (int k = 0; k < 4; k++) srow[wv][k * 64 + lane] = accr[k];
    __syncthreads();
    {
        const float rs = srow[0][tid] + srow[1][tid] + srow[2][tid] + srow[3][tid];
        atomicAdd(&adj[base + it * TSZ + tid], rs);
    }
}

// finish: skipped-pair ssum correction from the SAME meta arrays, plus adjc
// unpermute (cinv gather), then softmax(adjusted) + weighted box sum.
#define FBLK 1024
__global__ __launch_bounds__(FBLK) void soft_nms_finish_kernel(
    const float4* __restrict__ sboxes,   // (B,N) sorted f32 boxes
    const float* __restrict__ sscores,   // (B,N) sorted f32 scores
    const float* __restrict__ adj,       // (B,N) row accum (x2-order)
    const float* __restrict__ adjc,      // (B,N) col accum (x1-order)
    const int* __restrict__ cinv,        // (B,N) x2-rank -> x1-pos (tile-rel)
    const float* __restrict__ minx1c, const float* __restrict__ maxx2c,  // (B,NT)
    const void* __restrict__ boxes_raw,  // only for output-dtype probe
    void* __restrict__ out)              // (B,4) dtype matches input
{
    constexpr int K  = NBOX / FBLK;             // 8 items per thread
    constexpr int NW = FBLK / 64;               // 16 waves
    __shared__ float sminx[NT], smaxx[NT], ssumT[NT], scorr[NT];
    __shared__ float smax_[NW];
    __shared__ float sred[NW][5];

    const int b    = blockIdx.x;
    const int tid  = threadIdx.x;
    const int lane = tid & 63;
    const int wv   = tid >> 6;
    const size_t base = (size_t)b * NBOX;

    const bool isf32 = wave_probe_is_f32(boxes_raw);

    if (tid < NT) {
        sminx[tid] = minx1c[b * NT + tid];
        smaxx[tid] = maxx2c[b * NT + tid];
    }
    // per-tile score sums: wave wv covers tiles 2wv, 2wv+1
#pragma unroll
    for (int tt = 0; tt < 2; tt++) {
        const int T = wv * 2 + tt;
        float sm = 0.0f;
#pragma unroll
        for (int q = 0; q < 4; q++) sm += sscores[base + T * TSZ + q * 64 + lane];
#pragma unroll
        for (int off = 32; off > 0; off >>= 1) sm += __shfl_down(sm, off);
        if (lane == 0) ssumT[T] = sm;
    }
    __syncthreads();
    if (tid < NT) {
        float c = 0.0f;
        for (int T2 = 0; T2 < NT; T2++) {
            const bool skip = (smaxx[tid] < sminx[T2]) || (smaxx[T2] < sminx[tid]);
            if (skip) c += ssumT[T2];
        }
        scorr[tid] = c;
    }
    __syncthreads();

    float av[K];
    float m = -3.4e38f;
#pragma unroll
    for (int k = 0; k < K; k++) {
        const int r = k * FBLK + tid;
        const int pos = cinv[base + r];                       // x1-pos in tile
        av[k] = adj[base + r] + adjc[base + (r & ~255) + pos] + scorr[r >> 8];
        m = fmaxf(m, av[k]);
    }
#pragma unroll
    for (int off = 32; off > 0; off >>= 1)
        m = fmaxf(m, __shfl_down(m, off));
    if (lane == 0) smax_[wv] = m;
    __syncthreads();
    float M = smax_[0];
#pragma unroll
    for (int w = 1; w < NW; w++) M = fmaxf(M, smax_[w]);

    const float L2E = 1.4426950408889634f;
    float es = 0.0f, s0 = 0.0f, s1 = 0.0f, s2 = 0.0f, s3 = 0.0f;
#pragma unroll
    for (int k = 0; k < K; k++) {
        const float e = __builtin_amdgcn_exp2f((av[k] - M) * L2E);
        const float4 u = sboxes[base + k * FBLK + tid];
        es += e;
        s0 += e * u.x;
        s1 += e * u.y;
        s2 += e * u.z;
        s3 += e * u.w;
    }
#pragma unroll
    for (int off = 32; off > 0; off >>= 1) {
        es += __shfl_down(es, off);
        s0 += __shfl_down(s0, off);
        s1 += __shfl_down(s1, off);
        s2 += __shfl_down(s2, off);
        s3 += __shfl_down(s3, off);
    }
    if (lane == 0) {
        sred[wv][0] = es; sred[wv][1] = s0; sred[wv][2] = s1;
        sred[wv][3] = s2; sred[wv][4] = s3;
    }
    __syncthreads();
    if (tid == 0) {
        float ES = 0.0f, o[4] = {0.0f, 0.0f, 0.0f, 0.0f};
#pragma unroll
        for (int w = 0; w < NW; w++) {
            ES   += sred[w][0];
            o[0] += sred[w][1];
            o[1] += sred[w][2];
            o[2] += sred[w][3];
            o[3] += sred[w][4];
        }
        const float inv = 1.0f / ES;
        if (isf32) {
            float* of = (float*)out;
            for (int c = 0; c < 4; c++) of[b * 4 + c] = o[c] * inv;
        } else {
            __hip_bfloat16* oh = (__hip_bfloat16*)out;
            for (int c = 0; c < 4; c++) oh[b * 4 + c] = __float2bfloat16(o[c] * inv);
        }
    }
}

extern "C" void kernel_launch(void* const* d_in, const int* in_sizes, int n_in,
                              void* d_out, int out_size, void* d_ws, size_t ws_size,
                              hipStream_t stream) {
    const void* boxes_raw  = d_in[0];   // (4,8192,4)
    const void* scores_raw = d_in[1];   // (4,8192)

    char* w = (char*)d_ws;
    float4* sboxes   = (float4*)w;                 w += (size_t)BATCH * NBOX * 16;
    float4* cboxes   = (float4*)w;                 w += (size_t)BATCH * NBOX * 16;
    float2* cas      = (float2*)w;                 w += (size_t)BATCH * NBOX * 8;
    float*  sscores  = (float*)w;                  w += (size_t)BATCH * NBOX * 4;
    float*  adj      = (float*)w;                  w += (size_t)BATCH * NBOX * 4;
    float*  adjc     = (float*)w;                  w += (size_t)BATCH * NBOX * 4;
    int*    cinv     = (int*)w;                    w += (size_t)BATCH * NBOX * 4;
    float*  minx1c   = (float*)w;                  w += (size_t)BATCH * NT * 4;
    float*  maxx2c   = (float*)w;                  w += (size_t)BATCH * NT * 4;
    float*  cgmin    = (float*)w;                  w += (size_t)BATCH * NT * 4 * 4;
    int*    pairlist = (int*)w;                    w += (size_t)BATCH * NPAIRS * 4;
    int*    count    = (int*)w;

    sort_kernel<<<dim3(BATCH * SUBS), dim3(STH), 0, stream>>>(
        boxes_raw, scores_raw, sboxes, sscores, adj, adjc, minx1c, maxx2c, pairlist, count);
    perm_kernel<<<dim3(BATCH * NT), dim3(TSZ), 0, stream>>>(
        sboxes, sscores, cboxes, cas, cinv, cgmin);
    soft_nms_adj_kernel<<<dim3(BATCH * NPAIRS), dim3(BLOCK), 0, stream>>>(
        sboxes, sscores, cboxes, cas, cgmin, pairlist, count, adj, adjc);
    soft_nms_finish_kernel<<<dim3(BATCH), dim3(FBLK), 0, stream>>>(
        sboxes, sscores, adj, adjc, cinv, minx1c, maxx2c, boxes_raw, d_out);
}

// Round 5
// 130.265 us; speedup vs baseline: 1.0799x; 1.0799x over previous
//
#include <hip/hip_runtime.h>
#include <hip/hip_bf16.h>

#define BATCH   4
#define NBOX    8192
#define TSZ     256                  // tile size (rows & cols)
#define NT      (NBOX / TSZ)         // 32 tiles per batch
#define NPAIRS  (NT * (NT + 1) / 2)  // 528 tile-pairs per batch
#define QSPLIT  4                    // col-quarters per pair -> 1-wave blocks
#define NBINS   2048
#define SUBS    8                    // sub-slices per batch for the sort
#define SUBSZ   (NBOX / SUBS)        // 1024 boxes per slice
#define STH     512                  // sort kernel threads

__device__ __forceinline__ float bf2f(unsigned short u) {
    union { unsigned int i; float f; } c;
    c.i = ((unsigned int)u) << 16;
    return c.f;
}

__device__ __forceinline__ bool box_plausible(float x1, float y1, float x2, float y2) {
    bool ok = (x1 == x1) && (y1 == y1) && (x2 == x2) && (y2 == y2);
    ok = ok && fabsf(x1) < 1e4f && fabsf(y1) < 1e4f && fabsf(x2) < 1e4f && fabsf(y2) < 1e4f;
    ok = ok && x1 >= -1.0f && x1 <= 300.0f && y1 >= -1.0f && y1 <= 300.0f;
    const float w = x2 - x1, h = y2 - y1;
    ok = ok && w >= -0.1f && w <= 80.0f && h >= -0.1f && h <= 80.0f;
    return ok;
}

// Wave-redundant dtype probe; all waves deterministically agree. true -> f32.
__device__ __forceinline__ bool wave_probe_is_f32(const void* boxes_raw) {
    const int lane = threadIdx.x & 63;
    const float* bf = (const float*)boxes_raw;
    const bool okf = box_plausible(bf[lane * 4 + 0], bf[lane * 4 + 1],
                                   bf[lane * 4 + 2], bf[lane * 4 + 3]);
    const unsigned short* bh = (const unsigned short*)boxes_raw;
    const bool okh = box_plausible(bf2f(bh[lane * 4 + 0]), bf2f(bh[lane * 4 + 1]),
                                   bf2f(bh[lane * 4 + 2]), bf2f(bh[lane * 4 + 3]));
    const unsigned long long mf = __ballot(okf);
    const unsigned long long mh = __ballot(okh);
    return __popcll(mf) >= __popcll(mh);
}

__device__ __forceinline__ float4 load_box(const void* boxes_raw, size_t idx, bool isf32) {
    if (isf32) {
        return reinterpret_cast<const float4*>(boxes_raw)[idx];
    } else {
        const ushort4 u = reinterpret_cast<const ushort4*>(boxes_raw)[idx];
        return make_float4(bf2f(u.x), bf2f(u.y), bf2f(u.z), bf2f(u.w));
    }
}

__device__ __forceinline__ float load_score(const void* scores_raw, size_t idx, bool isf32) {
    return isf32 ? ((const float*)scores_raw)[idx]
                 : bf2f(((const unsigned short*)scores_raw)[idx]);
}

// Sort key is x2: 2048 bins over [0,256), 0.125 units/bin.
__device__ __forceinline__ int key_bin(float v) {
    const int bb = (int)(v * 8.0f);
    return min(NBINS - 1, max(0, bb));
}

// exp(-iou/0.5) = exp2(iou * (-2 log2 e)); arg in [-2.886, 0] -> raw v_exp ok
#define CEXP (-2.8853900817779268f)

__device__ __forceinline__ float pair_weight(
    float ix1, float iy1, float ix2, float iy2, float iarea,
    const float4& bj, float jarea)
{
    float w = fminf(ix2, bj.z) - fmaxf(ix1, bj.x);
    float h = fminf(iy2, bj.w) - fmaxf(iy1, bj.y);
    w = fmaxf(w, 0.0f);
    h = fmaxf(h, 0.0f);
    const float inter = w * h;
    const float uni   = iarea + jarea - inter;          // >= ~1 always
    const float arg   = (CEXP * inter) * __builtin_amdgcn_rcpf(uni);
    return __builtin_amdgcn_exp2f(arg);
}

// Single fused sort kernel (32 blocks, 512 threads). Every block REDUNDANTLY
// histograms the full batch (deterministic -> identical in all blocks).
// Sort key x2; per-bin atomicMin(x1) provides tile-level min-x1 meta used for
// the pairlist + finish correction. (Verified rounds 2-4.)
__global__ __launch_bounds__(STH) void sort_kernel(
    const void* __restrict__ boxes_raw, const void* __restrict__ scores_raw,
    float4* __restrict__ sboxes, float* __restrict__ sscores,
    float* __restrict__ adj,                                  // (B,N) zeroed
    float* __restrict__ minx1c, float* __restrict__ maxx2c,   // (B,NT)
    int* __restrict__ pairlist, int* __restrict__ count)      // (B,NPAIRS),(B)
{
    __shared__ int hist[NBINS];          // full-batch counts -> then sex
    __shared__ int bmin[NBINS];          // per-bin min x1 bits (x1 >= 0 -> monotone)
    __shared__ int hist2[NBINS];         // earlier-subs counts -> then loff
    __shared__ int wsum[STH / 64];
    __shared__ float sminT[NT], smaxT[NT];
    __shared__ int scnt;

    const int b    = blockIdx.x / SUBS;
    const int sub  = blockIdx.x % SUBS;
    const int tid  = threadIdx.x;
    const int lane = tid & 63;
    const int wv   = tid >> 6;
    const bool isf32 = wave_probe_is_f32(boxes_raw);
    const size_t base = (size_t)b * NBOX;

#pragma unroll
    for (int i = 0; i < NBINS / STH; i++) {
        hist[i * STH + tid]  = 0;
        bmin[i * STH + tid]  = 0x7f800000;   // +inf
        hist2[i * STH + tid] = 0;
    }
    if (tid == 0) scnt = 0;
    {   // zero adj: 32 blocks x 1024 floats covers B*NBOX
        const size_t z = (size_t)blockIdx.x * 1024;
        adj[z + tid] = 0.0f;
        adj[z + STH + tid] = 0.0f;
    }
    __syncthreads();

    // full-batch histogram on x2 + per-bin min x1 (identical in every block),
    // with the earlier-subs histogram folded in (i < sub*SUBSZ prefix).
    const int sublim = sub * SUBSZ;
#pragma unroll
    for (int k = 0; k < NBOX / STH; k++) {
        const int i = k * STH + tid;
        const float4 bx = load_box(boxes_raw, base + i, isf32);
        const int bin = key_bin(bx.z);
        atomicAdd(&hist[bin], 1);
        atomicMin(&bmin[bin], __float_as_int(bx.x));
        if (i < sublim) atomicAdd(&hist2[bin], 1);
    }
    __syncthreads();

    // exclusive scan of hist: 4 bins/thread + wave shfl scan + cross-wave
    {
        int tot[4], cum[4];
        int run = 0;
#pragma unroll
        for (int i = 0; i < 4; i++) {
            tot[i] = hist[tid * 4 + i];
            run += tot[i]; cum[i] = run;
        }
        int v = run;
#pragma unroll
        for (int d = 1; d < 64; d <<= 1) {
            const int u = __shfl_up(v, d);
            if (lane >= d) v += u;
        }
        if (lane == 63) wsum[wv] = v;
        __syncthreads();
        int wb = 0;
        for (int w = 0; w < wv; w++) wb += wsum[w];
        const int tb = wb + v - run;                 // exclusive thread base
#pragma unroll
        for (int i = 0; i < 4; i++) {
            const int bin = tid * 4 + i;
            const int e = tb + cum[i] - tot[i];      // exclusive bin start
            const int m = hist2[bin];                // my-sub prefix in bin
            hist[bin]  = e;                          // sex (own bins only)
            hist2[bin] = e + m;                      // loff (own bins only)
        }
    }
    __syncthreads();

    // tile meta: binary search on sex (nondecreasing, sex[0]==0).
    if (tid < NT) {
        int p = tid * TSZ;
        int lo = 0, hi = NBINS - 1;
        while (lo < hi) { const int mid = (lo + hi + 1) >> 1;
                          if (hist[mid] <= p) lo = mid; else hi = mid - 1; }
        const int Bf = lo;
        p = tid * TSZ + TSZ - 1;
        lo = 0; hi = NBINS - 1;
        while (lo < hi) { const int mid = (lo + hi + 1) >> 1;
                          if (hist[mid] <= p) lo = mid; else hi = mid - 1; }
        const int Bl = lo;
        float mn = 3.4e38f;
        for (int q = Bf; q <= Bl; q++) mn = fminf(mn, __int_as_float(bmin[q]));
        const float mx = (float)(Bl + 1) * 0.125f;   // upper bound of tile max x2
        sminT[tid] = mn; smaxT[tid] = mx;
        if (sub == 0) {
            minx1c[b * NT + tid] = mn;
            maxx2c[b * NT + tid] = mx;
        }
    }
    __syncthreads();

    // compacted live pair list (sub==0 only; same compares finish will use)
    if (sub == 0) {
        for (int q = tid; q < NPAIRS; q += STH) {
            int p = q, it = 0;
            while (p >= NT - it) { p -= NT - it; it++; }
            const int jt = it + p;
            const bool live = !((smaxT[it] < sminT[jt]) || (smaxT[jt] < sminT[it]));
            if (live) {
                const int idx = atomicAdd(&scnt, 1);
                pairlist[b * NPAIRS + idx] = (it << 8) | jt;
            }
        }
    }

    // scatter my slice (by x2 bin)
#pragma unroll
    for (int k = 0; k < SUBSZ / STH; k++) {
        const int i = sub * SUBSZ + k * STH + tid;
        const float4 bx = load_box(boxes_raw, base + i, isf32);
        const float  sc = load_score(scores_raw, base + i, isf32);
        const int pos = atomicAdd(&hist2[key_bin(bx.z)], 1);
        sboxes[base + pos]  = bx;
        sscores[base + pos] = sc;
    }

    __syncthreads();
    if (sub == 0 && tid == 0) count[b] = scnt;
}

// adj over live tile-pairs, ONE WAVE PER BLOCK (r19). Each block handles a
// 256-row x 64-col quarter of a tile-pair. Rationale (rounds 0-4 evidence):
// duration was invariant (~49 us) under a 35% VALU-work reduction -> the
// kernel is stall-bound on the per-iteration ds_read->compute->shfl chain,
// with 4-wave barrier-coupled blocks providing too few independent waves to
// hide it. 1-wave blocks: no barriers, no LDS cross-wave combine, 4x more
// schedulable units (grid B*NPAIRS*4, ~18 live waves/CU). Same r15 math.
__global__ __launch_bounds__(64, 8) void soft_nms_adj_kernel(
    const float4* __restrict__ sboxes,   // (B,N) x2-sorted boxes
    const float* __restrict__ sscores,   // (B,N) x2-sorted scores
    const int* __restrict__ pairlist,    // (B,NPAIRS) compacted live pairs
    const int* __restrict__ count,       // (B)
    float* __restrict__ adj)             // (B,N) f32, zeroed
{
    __shared__ float4 sbox[64];           // col slice: x1,y1,x2,y2
    __shared__ float2 sas[64];            // col slice: area, score

    const int bid = blockIdx.x;
    const int b   = bid / (NPAIRS * QSPLIT);
    const int r   = bid % (NPAIRS * QSPLIT);
    const int p   = r >> 2;               // pair index
    const int q   = r & 3;                // col-quarter
    if (p >= count[b]) return;            // dead block: one scalar load
    const int pr = pairlist[b * NPAIRS + p];
    const int it = pr >> 8, jt = pr & 255;

    const int lane = threadIdx.x;         // 64-thread block == lane
    const size_t base = (size_t)b * NBOX;
    const int colg = jt * TSZ + q * 64;   // this block's 64-col window

    // stage col slice into LDS (single wave: DS-ordered, no barrier needed)
    {
        const float4 uj = sboxes[base + colg + lane];
        sbox[lane] = uj;
        sas[lane]  = make_float2((uj.z - uj.x) * (uj.w - uj.y),
                                 sscores[base + colg + lane]);
    }

    // rows: lane owns rows {k*64 + lane} of the i-tile
    float rx1[4], ry1[4], rx2[4], ry2[4], rar[4], rsc[4], accr[4];
#pragma unroll
    for (int k = 0; k < 4; k++) {
        const int ig = it * TSZ + k * 64 + lane;
        const float4 ui = sboxes[base + ig];
        rx1[k] = ui.x; ry1[k] = ui.y; rx2[k] = ui.z; ry2[k] = ui.w;
        rar[k] = (ui.z - ui.x) * (ui.w - ui.y);
        rsc[k] = sscores[base + ig];
        accr[k] = 0.0f;
    }

    if (it == jt) {
        // diagonal: full ordered pairs, row side only (includes i==j);
        // union over the 4 quarters covers all 256 cols.
#pragma unroll 2
        for (int t = 0; t < 64; t++) {
            const int idx = (lane + t) & 63;
            const float4 bj = sbox[idx];
            const float2 as = sas[idx];
#pragma unroll
            for (int k = 0; k < 4; k++) {
                const float e = pair_weight(rx1[k], ry1[k], rx2[k], ry2[k], rar[k], bj, as.x);
                accr[k] = fmaf(e, as.y, accr[k]);
            }
        }
    } else {
        // off-diagonal: symmetric; col accumulator rides in registers per lane
        float accc = 0.0f;
#pragma unroll 2
        for (int t = 0; t < 64; t++) {
            const int idx = (lane + t) & 63;
            const float4 bj = sbox[idx];       // rotated stride-1: conflict-free
            const float2 as = sas[idx];
            const float e0 = pair_weight(rx1[0], ry1[0], rx2[0], ry2[0], rar[0], bj, as.x);
            const float e1 = pair_weight(rx1[1], ry1[1], rx2[1], ry2[1], rar[1], bj, as.x);
            const float e2 = pair_weight(rx1[2], ry1[2], rx2[2], ry2[2], rar[2], bj, as.x);
            const float e3 = pair_weight(rx1[3], ry1[3], rx2[3], ry2[3], rar[3], bj, as.x);
            accr[0] = fmaf(e0, as.y, accr[0]);
            accr[1] = fmaf(e1, as.y, accr[1]);
            accr[2] = fmaf(e2, as.y, accr[2]);
            accr[3] = fmaf(e3, as.y, accr[3]);
            const float c = fmaf(e0, rsc[0], fmaf(e1, rsc[1], fmaf(e2, rsc[2], e3 * rsc[3])));
            accc += __shfl(c, (lane - t) & 63);    // owner lane (lane+t)&63 pulls
        }
        atomicAdd(&adj[base + colg + lane], accc);     // exclusive col window
    }

    // row partials: direct coalesced atomics (no cross-wave combine needed)
#pragma unroll
    for (int k = 0; k < 4; k++)
        atomicAdd(&adj[base + it * TSZ + k * 64 + lane], accr[k]);
}

// finish: skipped-pair ssum correction from the SAME meta arrays, then
// softmax(adjusted) + weighted box sum -> 4 outputs.
#define FBLK 1024
__global__ __launch_bounds__(FBLK) void soft_nms_finish_kernel(
    const float4* __restrict__ sboxes,   // (B,N) sorted f32 boxes
    const float* __restrict__ sscores,   // (B,N) sorted f32 scores
    const float* __restrict__ adj,       // (B,N) f32
    const float* __restrict__ minx1c, const float* __restrict__ maxx2c,  // (B,NT)
    const void* __restrict__ boxes_raw,  // only for output-dtype probe
    void* __restrict__ out)              // (B,4) dtype matches input
{
    constexpr int K  = NBOX / FBLK;             // 8 items per thread
    constexpr int NW = FBLK / 64;               // 16 waves
    __shared__ float sminx[NT], smaxx[NT], ssumT[NT], scorr[NT];
    __shared__ float smax_[NW];
    __shared__ float sred[NW][5];

    const int b    = blockIdx.x;
    const int tid  = threadIdx.x;
    const int lane = tid & 63;
    const int wv   = tid >> 6;
    const size_t base = (size_t)b * NBOX;

    const bool isf32 = wave_probe_is_f32(boxes_raw);

    if (tid < NT) {
        sminx[tid] = minx1c[b * NT + tid];
        smaxx[tid] = maxx2c[b * NT + tid];
    }
    // per-tile score sums: wave wv covers tiles 2wv, 2wv+1
#pragma unroll
    for (int tt = 0; tt < 2; tt++) {
        const int T = wv * 2 + tt;
        float sm = 0.0f;
#pragma unroll
        for (int q = 0; q < 4; q++) sm += sscores[base + T * TSZ + q * 64 + lane];
#pragma unroll
        for (int off = 32; off > 0; off >>= 1) sm += __shfl_down(sm, off);
        if (lane == 0) ssumT[T] = sm;
    }
    __syncthreads();
    if (tid < NT) {
        float c = 0.0f;
        for (int T2 = 0; T2 < NT; T2++) {
            const bool skip = (smaxx[tid] < sminx[T2]) || (smaxx[T2] < sminx[tid]);
            if (skip) c += ssumT[T2];
        }
        scorr[tid] = c;
    }
    __syncthreads();

    float av[K];
    float m = -3.4e38f;
#pragma unroll
    for (int k = 0; k < K; k++) {
        const int r = k * FBLK + tid;
        av[k] = adj[base + r] + scorr[r >> 8];
        m = fmaxf(m, av[k]);
    }
#pragma unroll
    for (int off = 32; off > 0; off >>= 1)
        m = fmaxf(m, __shfl_down(m, off));
    if (lane == 0) smax_[wv] = m;
    __syncthreads();
    float M = smax_[0];
#pragma unroll
    for (int w = 1; w < NW; w++) M = fmaxf(M, smax_[w]);

    const float L2E = 1.4426950408889634f;
    float es = 0.0f, s0 = 0.0f, s1 = 0.0f, s2 = 0.0f, s3 = 0.0f;
#pragma unroll
    for (int k = 0; k < K; k++) {
        const float e = __builtin_amdgcn_exp2f((av[k] - M) * L2E);
        const float4 u = sboxes[base + k * FBLK + tid];
        es += e;
        s0 += e * u.x;
        s1 += e * u.y;
        s2 += e * u.z;
        s3 += e * u.w;
    }
#pragma unroll
    for (int off = 32; off > 0; off >>= 1) {
        es += __shfl_down(es, off);
        s0 += __shfl_down(s0, off);
        s1 += __shfl_down(s1, off);
        s2 += __shfl_down(s2, off);
        s3 += __shfl_down(s3, off);
    }
    if (lane == 0) {
        sred[wv][0] = es; sred[wv][1] = s0; sred[wv][2] = s1;
        sred[wv][3] = s2; sred[wv][4] = s3;
    }
    __syncthreads();
    if (tid == 0) {
        float ES = 0.0f, o[4] = {0.0f, 0.0f, 0.0f, 0.0f};
#pragma unroll
        for (int w = 0; w < NW; w++) {
            ES   += sred[w][0];
            o[0] += sred[w][1];
            o[1] += sred[w][2];
            o[2] += sred[w][3];
            o[3] += sred[w][4];
        }
        const float inv = 1.0f / ES;
        if (isf32) {
            float* of = (float*)out;
            for (int c = 0; c < 4; c++) of[b * 4 + c] = o[c] * inv;
        } else {
            __hip_bfloat16* oh = (__hip_bfloat16*)out;
            for (int c = 0; c < 4; c++) oh[b * 4 + c] = __float2bfloat16(o[c] * inv);
        }
    }
}

extern "C" void kernel_launch(void* const* d_in, const int* in_sizes, int n_in,
                              void* d_out, int out_size, void* d_ws, size_t ws_size,
                              hipStream_t stream) {
    const void* boxes_raw  = d_in[0];   // (4,8192,4)
    const void* scores_raw = d_in[1];   // (4,8192)

    char* w = (char*)d_ws;
    float4* sboxes   = (float4*)w;                 w += (size_t)BATCH * NBOX * 16;
    float*  sscores  = (float*)w;                  w += (size_t)BATCH * NBOX * 4;
    float*  adj      = (float*)w;                  w += (size_t)BATCH * NBOX * 4;
    float*  minx1c   = (float*)w;                  w += (size_t)BATCH * NT * 4;
    float*  maxx2c   = (float*)w;                  w += (size_t)BATCH * NT * 4;
    int*    pairlist = (int*)w;                    w += (size_t)BATCH * NPAIRS * 4;
    int*    count    = (int*)w;

    sort_kernel<<<dim3(BATCH * SUBS), dim3(STH), 0, stream>>>(
        boxes_raw, scores_raw, sboxes, sscores, adj, minx1c, maxx2c, pairlist, count);
    soft_nms_adj_kernel<<<dim3(BATCH * NPAIRS * QSPLIT), dim3(64), 0, stream>>>(
        sboxes, sscores, pairlist, count, adj);
    soft_nms_finish_kernel<<<dim3(BATCH), dim3(FBLK), 0, stream>>>(
        sboxes, sscores, adj, minx1c, maxx2c, boxes_raw, d_out);
}

// Round 6
// 129.231 us; speedup vs baseline: 1.0886x; 1.0080x over previous
//
#include <hip/hip_runtime.h>
#include <hip/hip_bf16.h>

#define BATCH   4
#define NBOX    8192
#define BLOCK   256
#define TSZ     256                  // tile size (rows & cols)
#define NT      (NBOX / TSZ)         // 32 tiles per batch
#define NPAIRS  (NT * (NT + 1) / 2)  // 528 tile-pairs per batch
#define NBINS   2048
#define SUBS    8                    // sub-slices per batch for the sort
#define SUBSZ   (NBOX / SUBS)        // 1024 boxes per slice
#define STH     512                  // sort kernel threads

__device__ __forceinline__ float bf2f(unsigned short u) {
    union { unsigned int i; float f; } c;
    c.i = ((unsigned int)u) << 16;
    return c.f;
}

__device__ __forceinline__ bool box_plausible(float x1, float y1, float x2, float y2) {
    bool ok = (x1 == x1) && (y1 == y1) && (x2 == x2) && (y2 == y2);
    ok = ok && fabsf(x1) < 1e4f && fabsf(y1) < 1e4f && fabsf(x2) < 1e4f && fabsf(y2) < 1e4f;
    ok = ok && x1 >= -1.0f && x1 <= 300.0f && y1 >= -1.0f && y1 <= 300.0f;
    const float w = x2 - x1, h = y2 - y1;
    ok = ok && w >= -0.1f && w <= 80.0f && h >= -0.1f && h <= 80.0f;
    return ok;
}

// Wave-redundant dtype probe; all waves deterministically agree. true -> f32.
__device__ __forceinline__ bool wave_probe_is_f32(const void* boxes_raw) {
    const int lane = threadIdx.x & 63;
    const float* bf = (const float*)boxes_raw;
    const bool okf = box_plausible(bf[lane * 4 + 0], bf[lane * 4 + 1],
                                   bf[lane * 4 + 2], bf[lane * 4 + 3]);
    const unsigned short* bh = (const unsigned short*)boxes_raw;
    const bool okh = box_plausible(bf2f(bh[lane * 4 + 0]), bf2f(bh[lane * 4 + 1]),
                                   bf2f(bh[lane * 4 + 2]), bf2f(bh[lane * 4 + 3]));
    const unsigned long long mf = __ballot(okf);
    const unsigned long long mh = __ballot(okh);
    return __popcll(mf) >= __popcll(mh);
}

__device__ __forceinline__ float4 load_box(const void* boxes_raw, size_t idx, bool isf32) {
    if (isf32) {
        return reinterpret_cast<const float4*>(boxes_raw)[idx];
    } else {
        const ushort4 u = reinterpret_cast<const ushort4*>(boxes_raw)[idx];
        return make_float4(bf2f(u.x), bf2f(u.y), bf2f(u.z), bf2f(u.w));
    }
}

__device__ __forceinline__ float load_score(const void* scores_raw, size_t idx, bool isf32) {
    return isf32 ? ((const float*)scores_raw)[idx]
                 : bf2f(((const unsigned short*)scores_raw)[idx]);
}

// Sort key is x2: 2048 bins over [0,256), 0.125 units/bin.
__device__ __forceinline__ int key_bin(float v) {
    const int bb = (int)(v * 8.0f);
    return min(NBINS - 1, max(0, bb));
}

// exp(-iou/0.5) = exp2(iou * (-2 log2 e)); arg in [-2.886, 0] -> raw v_exp ok
#define CEXP (-2.8853900817779268f)

__device__ __forceinline__ float pair_weight(
    float ix1, float iy1, float ix2, float iy2, float iarea,
    const float4& bj, float jarea)
{
    float w = fminf(ix2, bj.z) - fmaxf(ix1, bj.x);
    float h = fminf(iy2, bj.w) - fmaxf(iy1, bj.y);
    w = fmaxf(w, 0.0f);
    h = fmaxf(h, 0.0f);
    const float inter = w * h;
    const float uni   = iarea + jarea - inter;          // >= ~1 always
    const float arg   = (CEXP * inter) * __builtin_amdgcn_rcpf(uni);
    return __builtin_amdgcn_exp2f(arg);
}

// Single fused sort kernel (32 blocks, 512 threads). Every block REDUNDANTLY
// histograms the full batch (deterministic -> identical in all blocks).
// Sort key x2; per-bin atomicMin(x1) provides tile-level min-x1 meta used for
// the pairlist + finish correction. (Verified rounds 2-5.)
__global__ __launch_bounds__(STH) void sort_kernel(
    const void* __restrict__ boxes_raw, const void* __restrict__ scores_raw,
    float4* __restrict__ sboxes, float* __restrict__ sscores,
    float* __restrict__ adj,                                  // (B,N) zeroed
    float* __restrict__ minx1c, float* __restrict__ maxx2c,   // (B,NT)
    int* __restrict__ pairlist, int* __restrict__ count)      // (B,NPAIRS),(B)
{
    __shared__ int hist[NBINS];          // full-batch counts -> then sex
    __shared__ int bmin[NBINS];          // per-bin min x1 bits (x1 >= 0 -> monotone)
    __shared__ int hist2[NBINS];         // earlier-subs counts -> then loff
    __shared__ int wsum[STH / 64];
    __shared__ float sminT[NT], smaxT[NT];
    __shared__ int scnt;

    const int b    = blockIdx.x / SUBS;
    const int sub  = blockIdx.x % SUBS;
    const int tid  = threadIdx.x;
    const int lane = tid & 63;
    const int wv   = tid >> 6;
    const bool isf32 = wave_probe_is_f32(boxes_raw);
    const size_t base = (size_t)b * NBOX;

#pragma unroll
    for (int i = 0; i < NBINS / STH; i++) {
        hist[i * STH + tid]  = 0;
        bmin[i * STH + tid]  = 0x7f800000;   // +inf
        hist2[i * STH + tid] = 0;
    }
    if (tid == 0) scnt = 0;
    {   // zero adj: 32 blocks x 1024 floats covers B*NBOX
        const size_t z = (size_t)blockIdx.x * 1024;
        adj[z + tid] = 0.0f;
        adj[z + STH + tid] = 0.0f;
    }
    __syncthreads();

    // full-batch histogram on x2 + per-bin min x1 (identical in every block),
    // with the earlier-subs histogram folded in (i < sub*SUBSZ prefix).
    const int sublim = sub * SUBSZ;
#pragma unroll
    for (int k = 0; k < NBOX / STH; k++) {
        const int i = k * STH + tid;
        const float4 bx = load_box(boxes_raw, base + i, isf32);
        const int bin = key_bin(bx.z);
        atomicAdd(&hist[bin], 1);
        atomicMin(&bmin[bin], __float_as_int(bx.x));
        if (i < sublim) atomicAdd(&hist2[bin], 1);
    }
    __syncthreads();

    // exclusive scan of hist: 4 bins/thread + wave shfl scan + cross-wave
    {
        int tot[4], cum[4];
        int run = 0;
#pragma unroll
        for (int i = 0; i < 4; i++) {
            tot[i] = hist[tid * 4 + i];
            run += tot[i]; cum[i] = run;
        }
        int v = run;
#pragma unroll
        for (int d = 1; d < 64; d <<= 1) {
            const int u = __shfl_up(v, d);
            if (lane >= d) v += u;
        }
        if (lane == 63) wsum[wv] = v;
        __syncthreads();
        int wb = 0;
        for (int w = 0; w < wv; w++) wb += wsum[w];
        const int tb = wb + v - run;                 // exclusive thread base
#pragma unroll
        for (int i = 0; i < 4; i++) {
            const int bin = tid * 4 + i;
            const int e = tb + cum[i] - tot[i];      // exclusive bin start
            const int m = hist2[bin];                // my-sub prefix in bin
            hist[bin]  = e;                          // sex (own bins only)
            hist2[bin] = e + m;                      // loff (own bins only)
        }
    }
    __syncthreads();

    // tile meta: binary search on sex (nondecreasing, sex[0]==0).
    if (tid < NT) {
        int p = tid * TSZ;
        int lo = 0, hi = NBINS - 1;
        while (lo < hi) { const int mid = (lo + hi + 1) >> 1;
                          if (hist[mid] <= p) lo = mid; else hi = mid - 1; }
        const int Bf = lo;
        p = tid * TSZ + TSZ - 1;
        lo = 0; hi = NBINS - 1;
        while (lo < hi) { const int mid = (lo + hi + 1) >> 1;
                          if (hist[mid] <= p) lo = mid; else hi = mid - 1; }
        const int Bl = lo;
        float mn = 3.4e38f;
        for (int q = Bf; q <= Bl; q++) mn = fminf(mn, __int_as_float(bmin[q]));
        const float mx = (float)(Bl + 1) * 0.125f;   // upper bound of tile max x2
        sminT[tid] = mn; smaxT[tid] = mx;
        if (sub == 0) {
            minx1c[b * NT + tid] = mn;
            maxx2c[b * NT + tid] = mx;
        }
    }
    __syncthreads();

    // compacted live pair list (sub==0 only; same compares finish will use)
    if (sub == 0) {
        for (int q = tid; q < NPAIRS; q += STH) {
            int p = q, it = 0;
            while (p >= NT - it) { p -= NT - it; it++; }
            const int jt = it + p;
            const bool live = !((smaxT[it] < sminT[jt]) || (smaxT[jt] < sminT[it]));
            if (live) {
                const int idx = atomicAdd(&scnt, 1);
                pairlist[b * NPAIRS + idx] = (it << 8) | jt;
            }
        }
    }

    // scatter my slice (by x2 bin)
#pragma unroll
    for (int k = 0; k < SUBSZ / STH; k++) {
        const int i = sub * SUBSZ + k * STH + tid;
        const float4 bx = load_box(boxes_raw, base + i, isf32);
        const float  sc = load_score(scores_raw, base + i, isf32);
        const int pos = atomicAdd(&hist2[key_bin(bx.z)], 1);
        sboxes[base + pos]  = bx;
        sscores[base + pos] = sc;
    }

    __syncthreads();
    if (sub == 0 && tid == 0) count[b] = scnt;
}

// adj over live tile-pairs (r20 = r15 structure + verified cell-skip, clean).
// Off-diagonal blocks x1-sort their j-tile's 256 cols IN LDS (rank-scan, no
// extra dispatch / arrays): wave wv owns x1-sorted colgroup wv with EXACT
// min-x1. Rows are x2-sorted globally: rowgroup k max-x2 = lane63 + 0.125 bin
// slack. Cell (k,wv) skipped iff rowmax_x2[k] < colgroup_min_x1[wv] -> all
// its pairs have weight exactly 1 -> exact corrections (verified r3/r4):
//   rows of skipped cells: wave wv seeds its OWN colgroup score-sum (ws);
//     the cross-wave srow combine sums per-wave seeds exactly once.
//   wave's cols: ccorr = sum of skipped rowgroup score-sums.
// Col atomics target orig rank via LDS sidx (scatter stays inside the tile's
// own 1 KB window). Rows keep the one-atomic-per-row srow combine.
__global__ __launch_bounds__(BLOCK, 4) void soft_nms_adj_kernel(
    const float4* __restrict__ sboxes,   // (B,N) x2-sorted boxes
    const float* __restrict__ sscores,   // (B,N) x2-sorted scores
    const int* __restrict__ pairlist,    // (B,NPAIRS) compacted live pairs
    const int* __restrict__ count,       // (B)
    float* __restrict__ adj)             // (B,N) f32, zeroed
{
    __shared__ float4 sbox[TSZ];          // j-tile cols (x1-sorted if offdiag)
    __shared__ float2 sas[TSZ];           // j-tile cols: area, score
    __shared__ int    sidx[TSZ];          // x1-pos -> orig tile-rel idx
    __shared__ float  srow[4][TSZ];       // skey alias + per-wave row partials
    __shared__ float  cgminS[4];          // exact colgroup min x1

    const int bid = blockIdx.x;
    const int b   = bid / NPAIRS;
    const int p   = bid % NPAIRS;
    if (p >= count[b]) return;            // dead block: one scalar load
    const int pr = pairlist[b * NPAIRS + p];
    const int it = pr >> 8, jt = pr & 255;

    const int tid  = threadIdx.x;
    const int lane = tid & 63;
    const int wv   = tid >> 6;
    const size_t base = (size_t)b * NBOX;

    // rows: thread owns rows {k*64 + lane} of the i-tile (same set every wave)
    float rx1[4], ry1[4], rx2[4], ry2[4], rar[4], rsc[4], accr[4];
#pragma unroll
    for (int k = 0; k < 4; k++) {
        const int ig = it * TSZ + k * 64 + lane;
        const float4 ui = sboxes[base + ig];
        rx1[k] = ui.x; ry1[k] = ui.y; rx2[k] = ui.z; ry2[k] = ui.w;
        rar[k] = (ui.z - ui.x) * (ui.w - ui.y);
        rsc[k] = sscores[base + ig];
        accr[k] = 0.0f;
    }

    const int wvbase = wv * 64;
    const float4 uj = sboxes[base + jt * TSZ + tid];
    const float  jsc = sscores[base + jt * TSZ + tid];

    if (it == jt) {
        // diagonal: orig order, no sort, no skip; row side only (incl i==j)
        sbox[tid] = uj;
        sas[tid]  = make_float2((uj.z - uj.x) * (uj.w - uj.y), jsc);
        __syncthreads();
#pragma unroll 2
        for (int t = 0; t < 64; t++) {
            const int idx = wvbase + ((lane + t) & 63);
            const float4 bj = sbox[idx];
            const float2 as = sas[idx];
#pragma unroll
            for (int k = 0; k < 4; k++) {
                const float e = pair_weight(rx1[k], ry1[k], rx2[k], ry2[k], rar[k], bj, as.x);
                accr[k] = fmaf(e, as.y, accr[k]);
            }
        }
    } else {
        // ---- in-LDS x1 rank-sort of the j-tile cols ----
        float* skey = srow[0];            // alias (srow used only after loop)
        skey[tid] = uj.x;
        __syncthreads();
        int rank = 0;
#pragma unroll 8
        for (int j = 0; j < TSZ; j++) {
            const float v = skey[j];
            rank += (v < uj.x || (v == uj.x && j < tid)) ? 1 : 0;
        }
        __syncthreads();                  // skey fully read; safe to reuse srow
        sbox[rank] = uj;
        sas[rank]  = make_float2((uj.z - uj.x) * (uj.w - uj.y), jsc);
        sidx[rank] = tid;
        if ((rank & 63) == 0) cgminS[rank >> 6] = uj.x;
        __syncthreads();

        // ws = this wave's (x1-sorted) colgroup score sum
        float ws = sas[wvbase + lane].y;
#pragma unroll
        for (int off = 32; off > 0; off >>= 1) ws += __shfl_xor(ws, off);

        // per-wave cell-skip prefix in k (rowmax_x2 increasing with k)
        const float cg = cgminS[wv];
        int kstart = 0;
#pragma unroll
        for (int k = 0; k < 4; k++) {
            const float gmax = __shfl(rx2[k], 63) + 0.125f;  // bin slack
            if (kstart == k && gmax < cg) kstart = k + 1;
        }
        // col-side correction: sum of skipped rowgroup score sums
        float ccorr = 0.0f;
        if (kstart > 0) {
#pragma unroll
            for (int k = 0; k < 4; k++) {
                if (k < kstart) {
                    float gs = rsc[k];
#pragma unroll
                    for (int off = 32; off > 0; off >>= 1) gs += __shfl_xor(gs, off);
                    ccorr += gs;
                }
            }
        }
        // row-side seeds (this wave's skipped cells only)
#pragma unroll
        for (int k = 0; k < 4; k++) accr[k] = (k < kstart) ? ws : 0.0f;

        const int cj = sidx[wvbase + lane];            // orig tile-rel col idx

#define OFFD_LOOP(KS)                                                          \
        {                                                                      \
            float accc = ccorr;                                                \
            _Pragma("unroll 2")                                                \
            for (int t = 0; t < 64; t++) {                                     \
                const int idx = wvbase + ((lane + t) & 63);                    \
                const float4 bj = sbox[idx];                                   \
                const float2 as = sas[idx];                                    \
                float c = 0.0f;                                                \
                _Pragma("unroll")                                              \
                for (int k = KS; k < 4; ++k) {                                 \
                    const float e = pair_weight(rx1[k], ry1[k], rx2[k], ry2[k],\
                                                rar[k], bj, as.x);             \
                    accr[k] = fmaf(e, as.y, accr[k]);                          \
                    c = fmaf(e, rsc[k], c);                                    \
                }                                                              \
                accc += __shfl(c, (lane - t) & 63);                            \
            }                                                                  \
            atomicAdd(&adj[base + jt * TSZ + cj], accc);                       \
        }
        switch (kstart) {                 // wave-uniform; no barriers inside
            case 0: OFFD_LOOP(0); break;
            case 1: OFFD_LOOP(1); break;
            case 2: OFFD_LOOP(2); break;
            case 3: OFFD_LOOP(3); break;
            default:                      // fully skipped: corrections only
                atomicAdd(&adj[base + jt * TSZ + cj], ccorr);
                break;
        }
#undef OFFD_LOOP
    }

    // combine row partials across the 4 waves via LDS, one atomic per row
    __syncthreads();                      // all srow aliasing (skey) done
#pragma unroll
    for (int k = 0; k < 4; k++) srow[wv][k * 64 + lane] = accr[k];
    __syncthreads();
    {
        const float rs = srow[0][tid] + srow[1][tid] + srow[2][tid] + srow[3][tid];
        atomicAdd(&adj[base + it * TSZ + tid], rs);
    }
}

// finish: skipped-pair ssum correction from the SAME meta arrays, then
// softmax(adjusted) + weighted box sum -> 4 outputs.
#define FBLK 1024
__global__ __launch_bounds__(FBLK) void soft_nms_finish_kernel(
    const float4* __restrict__ sboxes,   // (B,N) sorted f32 boxes
    const float* __restrict__ sscores,   // (B,N) sorted f32 scores
    const float* __restrict__ adj,       // (B,N) f32
    const float* __restrict__ minx1c, const float* __restrict__ maxx2c,  // (B,NT)
    const void* __restrict__ boxes_raw,  // only for output-dtype probe
    void* __restrict__ out)              // (B,4) dtype matches input
{
    constexpr int K  = NBOX / FBLK;             // 8 items per thread
    constexpr int NW = FBLK / 64;               // 16 waves
    __shared__ float sminx[NT], smaxx[NT], ssumT[NT], scorr[NT];
    __shared__ float smax_[NW];
    __shared__ float sred[NW][5];

    const int b    = blockIdx.x;
    const int tid  = threadIdx.x;
    const int lane = tid & 63;
    const int wv   = tid >> 6;
    const size_t base = (size_t)b * NBOX;

    const bool isf32 = wave_probe_is_f32(boxes_raw);

    if (tid < NT) {
        sminx[tid] = minx1c[b * NT + tid];
        smaxx[tid] = maxx2c[b * NT + tid];
    }
    // per-tile score sums: wave wv covers tiles 2wv, 2wv+1
#pragma unroll
    for (int tt = 0; tt < 2; tt++) {
        const int T = wv * 2 + tt;
        float sm = 0.0f;
#pragma unroll
        for (int q = 0; q < 4; q++) sm += sscores[base + T * TSZ + q * 64 + lane];
#pragma unroll
        for (int off = 32; off > 0; off >>= 1) sm += __shfl_down(sm, off);
        if (lane == 0) ssumT[T] = sm;
    }
    __syncthreads();
    if (tid < NT) {
        float c = 0.0f;
        for (int T2 = 0; T2 < NT; T2++) {
            const bool skip = (smaxx[tid] < sminx[T2]) || (smaxx[T2] < sminx[tid]);
            if (skip) c += ssumT[T2];
        }
        scorr[tid] = c;
    }
    __syncthreads();

    float av[K];
    float m = -3.4e38f;
#pragma unroll
    for (int k = 0; k < K; k++) {
        const int r = k * FBLK + tid;
        av[k] = adj[base + r] + scorr[r >> 8];
        m = fmaxf(m, av[k]);
    }
#pragma unroll
    for (int off = 32; off > 0; off >>= 1)
        m = fmaxf(m, __shfl_down(m, off));
    if (lane == 0) smax_[wv] = m;
    __syncthreads();
    float M = smax_[0];
#pragma unroll
    for (int w = 1; w < NW; w++) M = fmaxf(M, smax_[w]);

    const float L2E = 1.4426950408889634f;
    float es = 0.0f, s0 = 0.0f, s1 = 0.0f, s2 = 0.0f, s3 = 0.0f;
#pragma unroll
    for (int k = 0; k < K; k++) {
        const float e = __builtin_amdgcn_exp2f((av[k] - M) * L2E);
        const float4 u = sboxes[base + k * FBLK + tid];
        es += e;
        s0 += e * u.x;
        s1 += e * u.y;
        s2 += e * u.z;
        s3 += e * u.w;
    }
#pragma unroll
    for (int off = 32; off > 0; off >>= 1) {
        es += __shfl_down(es, off);
        s0 += __shfl_down(s0, off);
        s1 += __shfl_down(s1, off);
        s2 += __shfl_down(s2, off);
        s3 += __shfl_down(s3, off);
    }
    if (lane == 0) {
        sred[wv][0] = es; sred[wv][1] = s0; sred[wv][2] = s1;
        sred[wv][3] = s2; sred[wv][4] = s3;
    }
    __syncthreads();
    if (tid == 0) {
        float ES = 0.0f, o[4] = {0.0f, 0.0f, 0.0f, 0.0f};
#pragma unroll
        for (int w = 0; w < NW; w++) {
            ES   += sred[w][0];
            o[0] += sred[w][1];
            o[1] += sred[w][2];
            o[2] += sred[w][3];
            o[3] += sred[w][4];
        }
        const float inv = 1.0f / ES;
        if (isf32) {
            float* of = (float*)out;
            for (int c = 0; c < 4; c++) of[b * 4 + c] = o[c] * inv;
        } else {
            __hip_bfloat16* oh = (__hip_bfloat16*)out;
            for (int c = 0; c < 4; c++) oh[b * 4 + c] = __float2bfloat16(o[c] * inv);
        }
    }
}

extern "C" void kernel_launch(void* const* d_in, const int* in_sizes, int n_in,
                              void* d_out, int out_size, void* d_ws, size_t ws_size,
                              hipStream_t stream) {
    const void* boxes_raw  = d_in[0];   // (4,8192,4)
    const void* scores_raw = d_in[1];   // (4,8192)

    char* w = (char*)d_ws;
    float4* sboxes   = (float4*)w;                 w += (size_t)BATCH * NBOX * 16;
    float*  sscores  = (float*)w;                  w += (size_t)BATCH * NBOX * 4;
    float*  adj      = (float*)w;                  w += (size_t)BATCH * NBOX * 4;
    float*  minx1c   = (float*)w;                  w += (size_t)BATCH * NT * 4;
    float*  maxx2c   = (float*)w;                  w += (size_t)BATCH * NT * 4;
    int*    pairlist = (int*)w;                    w += (size_t)BATCH * NPAIRS * 4;
    int*    count    = (int*)w;

    sort_kernel<<<dim3(BATCH * SUBS), dim3(STH), 0, stream>>>(
        boxes_raw, scores_raw, sboxes, sscores, adj, minx1c, maxx2c, pairlist, count);
    soft_nms_adj_kernel<<<dim3(BATCH * NPAIRS), dim3(BLOCK), 0, stream>>>(
        sboxes, sscores, pairlist, count, adj);
    soft_nms_finish_kernel<<<dim3(BATCH), dim3(FBLK), 0, stream>>>(
        sboxes, sscores, adj, minx1c, maxx2c, boxes_raw, d_out);
}